// Round 15
// baseline (195.898 us; speedup 1.0000x reference)
//
#include <hip/hip_runtime.h>

// ---------- types ----------
typedef __attribute__((ext_vector_type(8))) _Float16 half8;   // 8 x fp16 (4 VGPR)
typedef __attribute__((ext_vector_type(4)))  float   floatx4;
typedef __attribute__((ext_vector_type(2)))  float   floatx2;
typedef unsigned short ushort;

// ---------- async global->LDS 16B (wave-uniform LDS base + lane*16) ----------
__device__ __forceinline__ void gl_lds16(const void* g, void* lds) {
    __builtin_amdgcn_global_load_lds(
        (const __attribute__((address_space(1))) unsigned int*)g,
        (__attribute__((address_space(3))) unsigned int*)lds,
        16, 0, 0);
}

// ---------- bijective XCD swizzle (m204): same-XCD blocks -> adjacent tiles ----
__device__ __forceinline__ int xcd_swizzle(int orig, int nwg) {
    // requires nwg % 8 == 0 (all our grids satisfy this)
    int cpx = nwg >> 3;                 // chunks per XCD
    return (orig & 7) * cpx + (orig >> 3);
}

// ---------- prep: split fp32 -> fp16 hi + scaled fp16 lo (R5 scheme) ----------
// x = h + l/4096 + eps ; l = fp16((x-h)*4096) stays fp16-NORMAL (|l| ~ |x|).
// DUAL-ACC REQUIRED (R14 lesson): correction terms must accumulate in their
// own fp32 acc (error ~2e-7); a single shared acc rounds corrections against
// the 2^12-larger hh partial sums (~7e-7) and flips the dataset's tightest
// top-k tie (R6/R14 failed identically at 1.196e-2).
__global__ void split_all_kernel(const float* __restrict__ x,
                                 const float* __restrict__ Wq,
                                 const float* __restrict__ keys,
                                 _Float16* __restrict__ xh, _Float16* __restrict__ xl,
                                 _Float16* __restrict__ wh, _Float16* __restrict__ wl,
                                 _Float16* __restrict__ kh, _Float16* __restrict__ kl) {
    int b = blockIdx.x;
    const float* src; _Float16 *ph, *pl; int i;
    if (b < 1024)      { src = x;    ph = xh; pl = xl; i = b * 256 + threadIdx.x; }
    else if (b < 2048) { src = Wq;   ph = wh; pl = wl; i = (b - 1024) * 256 + threadIdx.x; }
    else               { src = keys; ph = kh; pl = kl; i = (b - 2048) * 256 + threadIdx.x; }
    const float* s = src + (size_t)i * 8;
    floatx4 a = *(const floatx4*)s;
    floatx4 bb = *(const floatx4*)(s + 4);
    float v[8];
    #pragma unroll
    for (int j = 0; j < 4; ++j) { v[j] = a[j]; v[j + 4] = bb[j]; }
    half8 vh, vl;
    #pragma unroll
    for (int j = 0; j < 8; ++j) {
        _Float16 h = (_Float16)v[j];
        _Float16 l = (_Float16)((v[j] - (float)h) * 4096.0f);
        vh[j] = h; vl[j] = l;
    }
    *(half8*)(ph + (size_t)i * 8) = vh;
    *(half8*)(pl + (size_t)i * 8) = vl;
}

// ---------- 2-plane fp16 GEMM:  C[M][N] = A[M][K] * B[N][K]^T ----------
// 3 MFMA terms: hh -> acc0 ; h*lB, lA*h -> acc1 ; C = acc0 + acc1/4096.
// 64x64 block, 4 waves, 32x32/wave, 2-buf dbuf, XCD swizzle, T5 setprio.
// (R13 config: best measured = 195.0 us.)
#define BM 64
#define BN 64
#define BK 32

template<int MODE>
__global__ __launch_bounds__(256, 4) void gemm2_kernel(
    const _Float16* __restrict__ Ah, const _Float16* __restrict__ Al, int lda,
    const _Float16* __restrict__ Bh, const _Float16* __restrict__ Bl, int ldb,
    int K, const float* __restrict__ bias, int nbx,
    float* __restrict__ C1, float* __restrict__ C2,
    _Float16* __restrict__ Qh, _Float16* __restrict__ Ql, int ldc)
{
    // [buf][plane][row][k] — linear 64B rows (global_load_lds requirement)
    __shared__ _Float16 As[2][2][BM][BK];   // 2 x 8 KB
    __shared__ _Float16 Bs[2][2][BN][BK];   // 2 x 8 KB

    const int tid  = threadIdx.x;
    const int lane = tid & 63;
    const int w    = tid >> 6;
    const int wr   = w >> 1;          // 0..1: M half (32 rows)
    const int wc   = w & 1;           // 0..1: N half (32 cols)

    // ---- XCD-swizzled tile coordinates (flattened x,y; z untouched) ----
    const int nwg  = nbx * gridDim.y;
    const int flat = xcd_swizzle(blockIdx.x + nbx * blockIdx.y, nwg);
    const int bx   = flat % nbx;
    const int by   = flat / nbx;

    const size_t aRow = (size_t)by * BM;
    const size_t bRow = (size_t)bx * BN;
    const _Float16 *Ah_p = Ah, *Al_p = Al, *Bh_p = Bh, *Bl_p = Bl;
    float* Cout = C1;
    if (MODE == 1) {
        int z = blockIdx.z;              // z = h*2 + c
        int h = z >> 1, c = z & 1;
        size_t aoff = (size_t)h * 512 + (size_t)c * 256;   // column slice of q
        Ah_p += aoff; Al_p += aoff;
        size_t boff = (size_t)z * 512 * (size_t)ldb;
        Bh_p += boff; Bl_p += boff;
        Cout = (c ? C2 : C1) + (size_t)h * 512;
    }

    // ---- staging constants (source pre-swizzle; HW-verified R5/R7/R9) ----
    const int rr = lane >> 2;                          // row within 16-row group
    const int jj = (lane & 3) ^ ((lane >> 3) & 3);     // global 16B chunk
    const size_t aStage = (aRow + rr) * (size_t)lda + jj * 8;
    const size_t bStage = (bRow + rr) * (size_t)ldb + jj * 8;

    // ---- fragment-read constants (swizzled LDS read; HW-verified) ----
    const int rchunk = (lane >> 4) ^ ((lane >> 1) & 3);
    const int arow0  = wr * 32 + (lane & 15);
    const int brow0  = wc * 32 + (lane & 15);

    // 16 wave-issues of 1KB; each wave issues exactly 4.
#define STAGE(buf, ktoff)                                                      \
    {                                                                          \
        _Float16* As0s = &As[buf][0][0][0];                                    \
        _Float16* Bs0s = &Bs[buf][0][0][0];                                    \
        for (int i = w; i < 16; i += 4) {                                      \
            if (i < 8) {                                                       \
                int p = i >> 2, g = i & 3;                                     \
                const _Float16* base = p ? Al_p : Ah_p;                        \
                gl_lds16(base + aStage + (size_t)(g * 16) * lda + (ktoff),     \
                         (void*)(As0s + p * (BM * BK) + g * 16 * BK));         \
            } else {                                                           \
                int j = i & 7;                                                 \
                int p = j >> 2, g = j & 3;                                     \
                const _Float16* base = p ? Bl_p : Bh_p;                        \
                gl_lds16(base + bStage + (size_t)(g * 16) * ldb + (ktoff),     \
                         (void*)(Bs0s + p * (BN * BK) + g * 16 * BK));         \
            }                                                                  \
        }                                                                      \
    }

    floatx4 acc0[2][2], acc1[2][2];
    #pragma unroll
    for (int m = 0; m < 2; ++m)
        #pragma unroll
        for (int n = 0; n < 2; ++n) { acc0[m][n] = (floatx4)0.0f; acc1[m][n] = (floatx4)0.0f; }

    const int NT = K / BK;

    // prologue: stage tile 0, barrier (drains vmcnt)
    STAGE(0, 0);
    __syncthreads();

    int cur = 0;
    for (int t = 0; t < NT; ++t) {
        if (t + 1 < NT) STAGE(cur ^ 1, (t + 1) * BK);   // prefetch next tile

        const _Float16* As0 = &As[cur][0][0][0];
        const _Float16* Bs0 = &Bs[cur][0][0][0];
        half8 a_h[2], a_l[2], b_h[2], b_l[2];
        #pragma unroll
        for (int m = 0; m < 2; ++m) {
            int off = (arow0 + m * 16) * BK + rchunk * 8;
            a_h[m] = *(const half8*)(As0 + off);
            a_l[m] = *(const half8*)(As0 + BM * BK + off);
        }
        #pragma unroll
        for (int n = 0; n < 2; ++n) {
            int off = (brow0 + n * 16) * BK + rchunk * 8;
            b_h[n] = *(const half8*)(Bs0 + off);
            b_l[n] = *(const half8*)(Bs0 + BN * BK + off);
        }
        __builtin_amdgcn_s_setprio(1);     // T5: favor MFMA-entering waves
        #pragma unroll
        for (int m = 0; m < 2; ++m)
            #pragma unroll
            for (int n = 0; n < 2; ++n) {
                acc0[m][n] = __builtin_amdgcn_mfma_f32_16x16x32_f16(a_h[m], b_h[n], acc0[m][n], 0, 0, 0);
                acc1[m][n] = __builtin_amdgcn_mfma_f32_16x16x32_f16(a_h[m], b_l[n], acc1[m][n], 0, 0, 0);
                acc1[m][n] = __builtin_amdgcn_mfma_f32_16x16x32_f16(a_l[m], b_h[n], acc1[m][n], 0, 0, 0);
            }
        __builtin_amdgcn_s_setprio(0);

        __syncthreads();   // single per-iter barrier
        cur ^= 1;
    }
#undef STAGE

    // ---- epilogue ----  (C/D: row=(lane>>4)*4+r, col=lane&15 — HW-verified)
    #pragma unroll
    for (int m = 0; m < 2; ++m)
        #pragma unroll
        for (int n = 0; n < 2; ++n)
            #pragma unroll
            for (int r = 0; r < 4; ++r) {
                size_t row = aRow + wr * 32 + m * 16 + (lane >> 4) * 4 + r;
                size_t col = bRow + wc * 32 + n * 16 + (lane & 15);
                float v = acc0[m][n][r] + acc1[m][n][r] * (1.0f / 4096.0f);
                if (MODE == 0) {
                    v += bias[col];
                    _Float16 h = (_Float16)v;
                    _Float16 l = (_Float16)((v - (float)h) * 4096.0f);
                    Qh[row * ldc + col] = h;
                    Ql[row * ldc + col] = l;
                } else {
                    Cout[row * ldc + col] = v;
                }
            }
}

// ---------- wave-wide top-16 (iterative argmax, ties -> lower index) ----------
template<int L>
__device__ __forceinline__ void wave_topk16_reg(float (&v)[L], int lane,
                                                float (&selv)[16], int (&seli)[16]) {
    #pragma unroll
    for (int s = 0; s < 16; ++s) {
        float bv = v[0]; int bj = 0;
        #pragma unroll
        for (int j = 1; j < L; ++j) if (v[j] > bv) { bv = v[j]; bj = j; }
        int bi = lane * L + bj;
        #pragma unroll
        for (int off = 32; off > 0; off >>= 1) {
            float ov = __shfl_xor(bv, off, 64);
            int   oi = __shfl_xor(bi, off, 64);
            if (ov > bv || (ov == bv && oi < bi)) { bv = ov; bi = oi; }
        }
        selv[s] = bv; seli[s] = bi;
        int lj = bi - lane * L;
        #pragma unroll
        for (int j = 0; j < L; ++j) if (j == lj) v[j] = -3.4e38f;
    }
}

// ---------- fused top-k + softmax + gather ----------
__global__ __launch_bounds__(256) void topk_gather_kernel(
    const float* __restrict__ s1, const float* __restrict__ s2,
    const float* __restrict__ values, float* __restrict__ out)
{
    __shared__ float sa[4][16];  __shared__ int ia_sh[4][16];
    __shared__ float sb[4][16];  __shared__ int ib_sh[4][16];
    __shared__ float wgt[4][16]; __shared__ int vidx[4][16];

    const int t = blockIdx.x, tid = threadIdx.x;
    const int h = tid >> 6, lane = tid & 63;

    const float* r1 = s1 + ((size_t)t * 4 + h) * 512;
    const float* r2 = s2 + ((size_t)t * 4 + h) * 512;
    float v1[8], v2[8];
    {
        floatx4 a0 = *(const floatx4*)(r1 + lane * 8);
        floatx4 a1 = *(const floatx4*)(r1 + lane * 8 + 4);
        floatx4 b0 = *(const floatx4*)(r2 + lane * 8);
        floatx4 b1 = *(const floatx4*)(r2 + lane * 8 + 4);
        #pragma unroll
        for (int j = 0; j < 4; ++j) { v1[j] = a0[j]; v1[j + 4] = a1[j]; v2[j] = b0[j]; v2[j + 4] = b1[j]; }
    }

    float selv1[16]; int seli1[16];
    wave_topk16_reg<8>(v1, lane, selv1, seli1);
    float selv2[16]; int seli2[16];
    wave_topk16_reg<8>(v2, lane, selv2, seli2);

    if (lane == 0) {
        #pragma unroll
        for (int s = 0; s < 16; ++s) {
            sa[h][s] = selv1[s]; ia_sh[h][s] = seli1[s];
            sb[h][s] = selv2[s]; ib_sh[h][s] = seli2[s];
        }
    }
    __syncthreads();

    // 256 combos: id = i*16 + j  (position order == reference flattened order)
    float cv[4];
    #pragma unroll
    for (int cc = 0; cc < 4; ++cc) {
        int id = lane * 4 + cc;
        cv[cc] = sa[h][id >> 4] + sb[h][id & 15];
    }
    float fs[16]; int fid[16];
    wave_topk16_reg<4>(cv, lane, fs, fid);

    if (lane == 0) {
        float m = fs[0], sum = 0.f, e[16];
        #pragma unroll
        for (int s = 0; s < 16; ++s) { e[s] = expf(fs[s] - m); sum += e[s]; }
        float inv = 1.f / sum;
        #pragma unroll
        for (int s = 0; s < 16; ++s) {
            int id = fid[s];
            wgt[h][s]  = e[s] * inv;
            vidx[h][s] = ia_sh[h][id >> 4] * 512 + ib_sh[h][id & 15];
        }
    }
    __syncthreads();

    // weighted gather: nontemporal values reads (use-once), deeper unroll
    const int col = tid * 2;
    float ax = 0.f, ay = 0.f;
    #pragma unroll 8
    for (int e2 = 0; e2 < 64; ++e2) {
        int hh = e2 >> 4, k = e2 & 15;
        float wv = wgt[hh][k];
        int   id = vidx[hh][k];
        const float* vp = values + (size_t)id * 512 + col;
        float v0 = __builtin_nontemporal_load(vp);
        float v1v = __builtin_nontemporal_load(vp + 1);
        ax += wv * v0; ay += wv * v1v;
    }
    float* op = out + (size_t)t * 512 + col;
    __builtin_nontemporal_store(ax, op);
    __builtin_nontemporal_store(ay, op + 1);
}

// ---------- launch ----------
extern "C" void kernel_launch(void* const* d_in, const int* in_sizes, int n_in,
                              void* d_out, int out_size, void* d_ws, size_t ws_size,
                              hipStream_t stream) {
    (void)in_sizes; (void)n_in; (void)out_size; (void)ws_size;
    const float* x      = (const float*)d_in[0];   // (2048, 1024)
    const float* Wq     = (const float*)d_in[1];   // (2048, 1024)
    const float* bq     = (const float*)d_in[2];   // (2048,)
    const float* keys   = (const float*)d_in[3];   // (4096, 256)
    const float* values = (const float*)d_in[4];   // (262144, 512)
    float* out = (float*)d_out;                    // (2048, 512)

    char* ws = (char*)d_ws;
    const size_t MB = 1024 * 1024;
    _Float16* xh = (_Float16*)(ws + 0 * MB);
    _Float16* xl = (_Float16*)(ws + 4 * MB);
    _Float16* wh = (_Float16*)(ws + 8 * MB);
    _Float16* wl = (_Float16*)(ws + 12 * MB);
    _Float16* kh = (_Float16*)(ws + 16 * MB);
    _Float16* kl = (_Float16*)(ws + 18 * MB);
    _Float16* qh = (_Float16*)(ws + 20 * MB);
    _Float16* ql = (_Float16*)(ws + 28 * MB);
    float*    s1 = (float*)(ws + 36 * MB);
    float*    s2 = (float*)(ws + 52 * MB);

    // 1) split all inputs to fp16 hi + scaled-lo planes (single launch)
    split_all_kernel<<<2560, 256, 0, stream>>>(x, Wq, keys, xh, xl, wh, wl, kh, kl);

    // 2) q = x @ Wq^T + bq   (M=2048, N=2048, K=1024) -> 2 fp16 planes
    gemm2_kernel<0><<<dim3(2048 / BN, 2048 / BM, 1), 256, 0, stream>>>(
        xh, xl, 1024, wh, wl, 1024, 1024, bq, 2048 / BN,
        nullptr, nullptr, qh, ql, 2048);

    // 3) scores per (h,c): s_c = q-slice @ keys-slice^T  (M=2048, N=512, K=256)
    gemm2_kernel<1><<<dim3(512 / BN, 2048 / BM, 8), 256, 0, stream>>>(
        qh, ql, 2048, kh, kl, 256, 256, nullptr, 512 / BN,
        s1, s2, nullptr, nullptr, 2048);

    // 4) fused top-16 x2 -> combine -> top-16 -> softmax -> weighted gather
    topk_gather_kernel<<<2048, 256, 0, stream>>>(s1, s2, values, out);
}

// Round 16
// 193.461 us; speedup vs baseline: 1.0126x; 1.0126x over previous
//
#include <hip/hip_runtime.h>

// ---------- types ----------
typedef __attribute__((ext_vector_type(8))) _Float16 half8;   // 8 x fp16 (4 VGPR)
typedef __attribute__((ext_vector_type(4)))  float   floatx4;
typedef __attribute__((ext_vector_type(2)))  float   floatx2;
typedef unsigned short ushort;

// ---------- async global->LDS 16B (wave-uniform LDS base + lane*16) ----------
__device__ __forceinline__ void gl_lds16(const void* g, void* lds) {
    __builtin_amdgcn_global_load_lds(
        (const __attribute__((address_space(1))) unsigned int*)g,
        (__attribute__((address_space(3))) unsigned int*)lds,
        16, 0, 0);
}

// ---------- bijective XCD swizzle (m204): same-XCD blocks -> adjacent tiles ----
__device__ __forceinline__ int xcd_swizzle(int orig, int nwg) {
    // requires nwg % 8 == 0 (all our grids satisfy this)
    int cpx = nwg >> 3;                 // chunks per XCD
    return (orig & 7) * cpx + (orig >> 3);
}

// ---------- prep: split fp32 -> fp16 hi + scaled fp16 lo (R5 scheme) ----------
// x = h + l/4096 + eps ; l = fp16((x-h)*4096) stays fp16-NORMAL (|l| ~ |x|).
// DUAL-ACC REQUIRED (R14 lesson): correction terms must accumulate in their
// own fp32 acc (error ~2e-7); a single shared acc rounds corrections against
// the 2^12-larger hh partial sums (~7e-7) and flips the dataset's tightest
// top-k tie (R6/R14 failed identically at 1.196e-2).
__global__ void split_all_kernel(const float* __restrict__ x,
                                 const float* __restrict__ Wq,
                                 const float* __restrict__ keys,
                                 _Float16* __restrict__ xh, _Float16* __restrict__ xl,
                                 _Float16* __restrict__ wh, _Float16* __restrict__ wl,
                                 _Float16* __restrict__ kh, _Float16* __restrict__ kl) {
    int b = blockIdx.x;
    const float* src; _Float16 *ph, *pl; int i;
    if (b < 1024)      { src = x;    ph = xh; pl = xl; i = b * 256 + threadIdx.x; }
    else if (b < 2048) { src = Wq;   ph = wh; pl = wl; i = (b - 1024) * 256 + threadIdx.x; }
    else               { src = keys; ph = kh; pl = kl; i = (b - 2048) * 256 + threadIdx.x; }
    const float* s = src + (size_t)i * 8;
    floatx4 a = *(const floatx4*)s;
    floatx4 bb = *(const floatx4*)(s + 4);
    float v[8];
    #pragma unroll
    for (int j = 0; j < 4; ++j) { v[j] = a[j]; v[j + 4] = bb[j]; }
    half8 vh, vl;
    #pragma unroll
    for (int j = 0; j < 8; ++j) {
        _Float16 h = (_Float16)v[j];
        _Float16 l = (_Float16)((v[j] - (float)h) * 4096.0f);
        vh[j] = h; vl[j] = l;
    }
    *(half8*)(ph + (size_t)i * 8) = vh;
    *(half8*)(pl + (size_t)i * 8) = vl;
}

// ---------- 2-plane fp16 GEMM:  C[M][N] = A[M][K] * B[N][K]^T ----------
// 3 MFMA terms: hh -> acc0 ; h*lB, lA*h -> acc1 ; C = acc0 + acc1/4096.
// 64x64 block, 4 waves, 32x32/wave, 2-buf dbuf, XCD swizzle, T5 setprio.
// (R13 config: best measured = 195.0 us.)
#define BM 64
#define BN 64
#define BK 32

template<int MODE>
__global__ __launch_bounds__(256, 4) void gemm2_kernel(
    const _Float16* __restrict__ Ah, const _Float16* __restrict__ Al, int lda,
    const _Float16* __restrict__ Bh, const _Float16* __restrict__ Bl, int ldb,
    int K, const float* __restrict__ bias, int nbx,
    float* __restrict__ C1, float* __restrict__ C2,
    _Float16* __restrict__ Qh, _Float16* __restrict__ Ql, int ldc)
{
    // [buf][plane][row][k] — linear 64B rows (global_load_lds requirement)
    __shared__ _Float16 As[2][2][BM][BK];   // 2 x 8 KB
    __shared__ _Float16 Bs[2][2][BN][BK];   // 2 x 8 KB

    const int tid  = threadIdx.x;
    const int lane = tid & 63;
    const int w    = tid >> 6;
    const int wr   = w >> 1;          // 0..1: M half (32 rows)
    const int wc   = w & 1;           // 0..1: N half (32 cols)

    // ---- XCD-swizzled tile coordinates (flattened x,y; z untouched) ----
    const int nwg  = nbx * gridDim.y;
    const int flat = xcd_swizzle(blockIdx.x + nbx * blockIdx.y, nwg);
    const int bx   = flat % nbx;
    const int by   = flat / nbx;

    const size_t aRow = (size_t)by * BM;
    const size_t bRow = (size_t)bx * BN;
    const _Float16 *Ah_p = Ah, *Al_p = Al, *Bh_p = Bh, *Bl_p = Bl;
    float* Cout = C1;
    if (MODE == 1) {
        int z = blockIdx.z;              // z = h*2 + c
        int h = z >> 1, c = z & 1;
        size_t aoff = (size_t)h * 512 + (size_t)c * 256;   // column slice of q
        Ah_p += aoff; Al_p += aoff;
        size_t boff = (size_t)z * 512 * (size_t)ldb;
        Bh_p += boff; Bl_p += boff;
        Cout = (c ? C2 : C1) + (size_t)h * 512;
    }

    // ---- staging constants (source pre-swizzle; HW-verified R5/R7/R9) ----
    const int rr = lane >> 2;                          // row within 16-row group
    const int jj = (lane & 3) ^ ((lane >> 3) & 3);     // global 16B chunk
    const size_t aStage = (aRow + rr) * (size_t)lda + jj * 8;
    const size_t bStage = (bRow + rr) * (size_t)ldb + jj * 8;

    // ---- fragment-read constants (swizzled LDS read; HW-verified) ----
    const int rchunk = (lane >> 4) ^ ((lane >> 1) & 3);
    const int arow0  = wr * 32 + (lane & 15);
    const int brow0  = wc * 32 + (lane & 15);

    // 16 wave-issues of 1KB; each wave issues exactly 4.
#define STAGE(buf, ktoff)                                                      \
    {                                                                          \
        _Float16* As0s = &As[buf][0][0][0];                                    \
        _Float16* Bs0s = &Bs[buf][0][0][0];                                    \
        for (int i = w; i < 16; i += 4) {                                      \
            if (i < 8) {                                                       \
                int p = i >> 2, g = i & 3;                                     \
                const _Float16* base = p ? Al_p : Ah_p;                        \
                gl_lds16(base + aStage + (size_t)(g * 16) * lda + (ktoff),     \
                         (void*)(As0s + p * (BM * BK) + g * 16 * BK));         \
            } else {                                                           \
                int j = i & 7;                                                 \
                int p = j >> 2, g = j & 3;                                     \
                const _Float16* base = p ? Bl_p : Bh_p;                        \
                gl_lds16(base + bStage + (size_t)(g * 16) * ldb + (ktoff),     \
                         (void*)(Bs0s + p * (BN * BK) + g * 16 * BK));         \
            }                                                                  \
        }                                                                      \
    }

    floatx4 acc0[2][2], acc1[2][2];
    #pragma unroll
    for (int m = 0; m < 2; ++m)
        #pragma unroll
        for (int n = 0; n < 2; ++n) { acc0[m][n] = (floatx4)0.0f; acc1[m][n] = (floatx4)0.0f; }

    const int NT = K / BK;

    // prologue: stage tile 0, barrier (drains vmcnt)
    STAGE(0, 0);
    __syncthreads();

    int cur = 0;
    for (int t = 0; t < NT; ++t) {
        if (t + 1 < NT) STAGE(cur ^ 1, (t + 1) * BK);   // prefetch next tile

        const _Float16* As0 = &As[cur][0][0][0];
        const _Float16* Bs0 = &Bs[cur][0][0][0];
        half8 a_h[2], a_l[2], b_h[2], b_l[2];
        #pragma unroll
        for (int m = 0; m < 2; ++m) {
            int off = (arow0 + m * 16) * BK + rchunk * 8;
            a_h[m] = *(const half8*)(As0 + off);
            a_l[m] = *(const half8*)(As0 + BM * BK + off);
        }
        #pragma unroll
        for (int n = 0; n < 2; ++n) {
            int off = (brow0 + n * 16) * BK + rchunk * 8;
            b_h[n] = *(const half8*)(Bs0 + off);
            b_l[n] = *(const half8*)(Bs0 + BN * BK + off);
        }
        __builtin_amdgcn_s_setprio(1);     // T5: favor MFMA-entering waves
        #pragma unroll
        for (int m = 0; m < 2; ++m)
            #pragma unroll
            for (int n = 0; n < 2; ++n) {
                acc0[m][n] = __builtin_amdgcn_mfma_f32_16x16x32_f16(a_h[m], b_h[n], acc0[m][n], 0, 0, 0);
                acc1[m][n] = __builtin_amdgcn_mfma_f32_16x16x32_f16(a_h[m], b_l[n], acc1[m][n], 0, 0, 0);
                acc1[m][n] = __builtin_amdgcn_mfma_f32_16x16x32_f16(a_l[m], b_h[n], acc1[m][n], 0, 0, 0);
            }
        __builtin_amdgcn_s_setprio(0);

        __syncthreads();   // single per-iter barrier
        cur ^= 1;
    }
#undef STAGE

    // ---- epilogue ----  (C/D: row=(lane>>4)*4+r, col=lane&15 — HW-verified)
    #pragma unroll
    for (int m = 0; m < 2; ++m)
        #pragma unroll
        for (int n = 0; n < 2; ++n)
            #pragma unroll
            for (int r = 0; r < 4; ++r) {
                size_t row = aRow + wr * 32 + m * 16 + (lane >> 4) * 4 + r;
                size_t col = bRow + wc * 32 + n * 16 + (lane & 15);
                float v = acc0[m][n][r] + acc1[m][n][r] * (1.0f / 4096.0f);
                if (MODE == 0) {
                    v += bias[col];
                    _Float16 h = (_Float16)v;
                    _Float16 l = (_Float16)((v - (float)h) * 4096.0f);
                    Qh[row * ldc + col] = h;
                    Ql[row * ldc + col] = l;
                } else {
                    Cout[row * ldc + col] = v;
                }
            }
}

// ---------- wave-wide top-16 (iterative argmax, ties -> lower index) ----------
template<int L>
__device__ __forceinline__ void wave_topk16_reg(float (&v)[L], int lane,
                                                float (&selv)[16], int (&seli)[16]) {
    #pragma unroll
    for (int s = 0; s < 16; ++s) {
        float bv = v[0]; int bj = 0;
        #pragma unroll
        for (int j = 1; j < L; ++j) if (v[j] > bv) { bv = v[j]; bj = j; }
        int bi = lane * L + bj;
        #pragma unroll
        for (int off = 32; off > 0; off >>= 1) {
            float ov = __shfl_xor(bv, off, 64);
            int   oi = __shfl_xor(bi, off, 64);
            if (ov > bv || (ov == bv && oi < bi)) { bv = ov; bi = oi; }
        }
        selv[s] = bv; seli[s] = bi;
        int lj = bi - lane * L;
        #pragma unroll
        for (int j = 0; j < L; ++j) if (j == lj) v[j] = -3.4e38f;
    }
}

// ---------- fused top-k + softmax + gather ----------
// R16: gather loads widened 8B -> 16B/lane (G13 sweet spot): thread-halves
// (pair = tid>>7) take odd/even rows with float4 loads, partials combined
// via a 2 KB LDS reduction, float4 nontemporal store.
__global__ __launch_bounds__(256) void topk_gather_kernel(
    const float* __restrict__ s1, const float* __restrict__ s2,
    const float* __restrict__ values, float* __restrict__ out)
{
    __shared__ float sa[4][16];  __shared__ int ia_sh[4][16];
    __shared__ float sb[4][16];  __shared__ int ib_sh[4][16];
    __shared__ float wgt[4][16]; __shared__ int vidx[4][16];
    __shared__ __align__(16) float red[512];   // pair-1 partials (128 x float4)

    const int t = blockIdx.x, tid = threadIdx.x;
    const int h = tid >> 6, lane = tid & 63;

    const float* r1 = s1 + ((size_t)t * 4 + h) * 512;
    const float* r2 = s2 + ((size_t)t * 4 + h) * 512;
    float v1[8], v2[8];
    {
        floatx4 a0 = *(const floatx4*)(r1 + lane * 8);
        floatx4 a1 = *(const floatx4*)(r1 + lane * 8 + 4);
        floatx4 b0 = *(const floatx4*)(r2 + lane * 8);
        floatx4 b1 = *(const floatx4*)(r2 + lane * 8 + 4);
        #pragma unroll
        for (int j = 0; j < 4; ++j) { v1[j] = a0[j]; v1[j + 4] = a1[j]; v2[j] = b0[j]; v2[j + 4] = b1[j]; }
    }

    float selv1[16]; int seli1[16];
    wave_topk16_reg<8>(v1, lane, selv1, seli1);
    float selv2[16]; int seli2[16];
    wave_topk16_reg<8>(v2, lane, selv2, seli2);

    if (lane == 0) {
        #pragma unroll
        for (int s = 0; s < 16; ++s) {
            sa[h][s] = selv1[s]; ia_sh[h][s] = seli1[s];
            sb[h][s] = selv2[s]; ib_sh[h][s] = seli2[s];
        }
    }
    __syncthreads();

    // 256 combos: id = i*16 + j  (position order == reference flattened order)
    float cv[4];
    #pragma unroll
    for (int cc = 0; cc < 4; ++cc) {
        int id = lane * 4 + cc;
        cv[cc] = sa[h][id >> 4] + sb[h][id & 15];
    }
    float fs[16]; int fid[16];
    wave_topk16_reg<4>(cv, lane, fs, fid);

    if (lane == 0) {
        float m = fs[0], sum = 0.f, e[16];
        #pragma unroll
        for (int s = 0; s < 16; ++s) { e[s] = expf(fs[s] - m); sum += e[s]; }
        float inv = 1.f / sum;
        #pragma unroll
        for (int s = 0; s < 16; ++s) {
            int id = fid[s];
            wgt[h][s]  = e[s] * inv;
            vidx[h][s] = ia_sh[h][id >> 4] * 512 + ib_sh[h][id & 15];
        }
    }
    __syncthreads();

    // ---- weighted gather: float4 per lane (16B), rows split odd/even ----
    const int pair = tid >> 7;          // 0: even rows, 1: odd rows
    const int cidx = tid & 127;         // 128 threads x 4 cols = 512
    const int col4 = cidx * 4;
    floatx4 a = (floatx4)0.0f;
    #pragma unroll 8
    for (int e2 = pair; e2 < 64; e2 += 2) {
        int hh = e2 >> 4, k = e2 & 15;
        float wv = wgt[hh][k];
        int   id = vidx[hh][k];
        const floatx4* vp = (const floatx4*)(values + (size_t)id * 512 + col4);
        floatx4 v = __builtin_nontemporal_load(vp);
        a += wv * v;
    }
    if (pair == 1) *(floatx4*)(&red[col4]) = a;
    __syncthreads();
    if (pair == 0) {
        floatx4 b = *(const floatx4*)(&red[col4]);
        a += b;
        __builtin_nontemporal_store(a, (floatx4*)(out + (size_t)t * 512 + col4));
    }
}

// ---------- launch ----------
extern "C" void kernel_launch(void* const* d_in, const int* in_sizes, int n_in,
                              void* d_out, int out_size, void* d_ws, size_t ws_size,
                              hipStream_t stream) {
    (void)in_sizes; (void)n_in; (void)out_size; (void)ws_size;
    const float* x      = (const float*)d_in[0];   // (2048, 1024)
    const float* Wq     = (const float*)d_in[1];   // (2048, 1024)
    const float* bq     = (const float*)d_in[2];   // (2048,)
    const float* keys   = (const float*)d_in[3];   // (4096, 256)
    const float* values = (const float*)d_in[4];   // (262144, 512)
    float* out = (float*)d_out;                    // (2048, 512)

    char* ws = (char*)d_ws;
    const size_t MB = 1024 * 1024;
    _Float16* xh = (_Float16*)(ws + 0 * MB);
    _Float16* xl = (_Float16*)(ws + 4 * MB);
    _Float16* wh = (_Float16*)(ws + 8 * MB);
    _Float16* wl = (_Float16*)(ws + 12 * MB);
    _Float16* kh = (_Float16*)(ws + 16 * MB);
    _Float16* kl = (_Float16*)(ws + 18 * MB);
    _Float16* qh = (_Float16*)(ws + 20 * MB);
    _Float16* ql = (_Float16*)(ws + 28 * MB);
    float*    s1 = (float*)(ws + 36 * MB);
    float*    s2 = (float*)(ws + 52 * MB);

    // 1) split all inputs to fp16 hi + scaled-lo planes (single launch)
    split_all_kernel<<<2560, 256, 0, stream>>>(x, Wq, keys, xh, xl, wh, wl, kh, kl);

    // 2) q = x @ Wq^T + bq   (M=2048, N=2048, K=1024) -> 2 fp16 planes
    gemm2_kernel<0><<<dim3(2048 / BN, 2048 / BM, 1), 256, 0, stream>>>(
        xh, xl, 1024, wh, wl, 1024, 1024, bq, 2048 / BN,
        nullptr, nullptr, qh, ql, 2048);

    // 3) scores per (h,c): s_c = q-slice @ keys-slice^T  (M=2048, N=512, K=256)
    gemm2_kernel<1><<<dim3(512 / BN, 2048 / BM, 8), 256, 0, stream>>>(
        qh, ql, 2048, kh, kl, 256, 256, nullptr, 512 / BN,
        s1, s2, nullptr, nullptr, 2048);

    // 4) fused top-16 x2 -> combine -> top-16 -> softmax -> weighted gather
    topk_gather_kernel<<<2048, 256, 0, stream>>>(s1, s2, values, out);
}